// Round 10
// baseline (256.182 us; speedup 1.0000x reference)
//
#include <hip/hip_runtime.h>
#include <hip/hip_cooperative_groups.h>
#include <math.h>

namespace cg = cooperative_groups;

// ClusterGCN 3-layer inference, MI355X — R25.
// R24 landed 208.1. Budget: kernels sum ~150us, ~55us = 5 launch boundaries +
// memset. R25: single cooperative kernel, phases {zero, prep/partition, fillb,
// L1, L2+HR, gather3} separated by grid.sync() (drains kept — they're
// semantically required — launches deleted). LDS = explicit 17.6KB union.
// Fallback to R24-style 6 dispatches if coop unavailable. Phase bodies are
// R24 verbatim -> bit-exact (absmax 0.03125).

constexpr int DK = 128;
constexpr int NBUCK = 256;
constexpr int ESTRIDE = 3584;   // max bucket count ~3136+6sigma~3470 < 3584
constexpr int EPB = 2048;       // edges per partition block (8/thread)
constexpr int SMEM_BYTES = 17600;

typedef __attribute__((ext_vector_type(8))) short bf16x8;
typedef __attribute__((ext_vector_type(4))) float f32x4;

__device__ inline unsigned short f2bf(float f) {
    unsigned int u; __builtin_memcpy(&u, &f, 4);
    unsigned int r = (u + 0x7FFFu + ((u >> 16) & 1u)) >> 16;
    return (unsigned short)r;
}
__device__ inline float blo(unsigned int u) {
    unsigned int t = u << 16; float f; __builtin_memcpy(&f, &t, 4); return f;
}
__device__ inline float bhi(unsigned int u) {
    unsigned int t = u & 0xffff0000u; float f; __builtin_memcpy(&f, &t, 4); return f;
}

struct KParams {
    const float4* x; uint2* xb2;
    const int* row; const int* col;
    int* bcnt; unsigned int* ebuf;
    int n4, E, bspan, npart, N;
    const float *W1o, *W1r, *W2o, *W2r, *W3o, *W3r;
    uint4 *wf1, *wf2, *wf3;
    int* offs; float* deginv; unsigned short* srow;
    const float *b1, *b2, *b3v;
    unsigned short *xbuf, *Ya, *Hb;
    float* Rb; float4* out;
    int phase;   // -1 = all phases (cooperative), else single phase
};

__device__ void wprep_body(const float* __restrict__ Wout, const float* __restrict__ Wroot,
                           uint4* __restrict__ frag, int dout, int tid) {
    int total = 8 * (dout >> 4) * 64;
    if (tid >= total) return;
    int L = tid & 63;
    int fu = (tid >> 6) % (dout >> 4);
    int t = (tid >> 6) / (dout >> 4);
    int quad = L >> 4, l15 = L & 15;
    int n = fu * 16 + l15;
    unsigned int p[4];
#pragma unroll
    for (int jj = 0; jj < 4; ++jj) {
        int k0 = t * 32 + quad * 8 + jj * 2;
        float v0 = (k0 < 128) ? Wout[k0 * dout + n] : Wroot[(k0 - 128) * dout + n];
        int k1 = k0 + 1;
        float v1 = (k1 < 128) ? Wout[k1 * dout + n] : Wroot[(k1 - 128) * dout + n];
        p[jj] = (unsigned)f2bf(v0) | ((unsigned)f2bf(v1) << 16);
    }
    frag[tid] = make_uint4(p[0], p[1], p[2], p[3]);
}

// ---- P0: edge partition (units 0..npart-1), weight swizzle, x-convert ------
__device__ void body_p0(const KParams& P, int u, unsigned char* smem) {
    const int tid = threadIdx.x;
    if (u < P.npart) {
        int* cnt  = (int*)smem;           // 256 ints
        int* base = (int*)(smem + 1024);  // 256 ints
        __syncthreads();                  // smem reuse guard across iterations
        const int t0 = u * EPB;
        cnt[tid] = 0;
        __syncthreads();
        int bk[EPB / 256];
#pragma unroll
        for (int k = 0; k < EPB / 256; ++k) {
            int i = t0 + k * 256 + tid;
            int bb = -1;
            if (i < P.E) { bb = P.col[i] / P.bspan; atomicAdd(&cnt[bb], 1); }
            bk[k] = bb;
        }
        __syncthreads();
        base[tid] = cnt[tid] ? atomicAdd(&P.bcnt[tid], cnt[tid]) : 0;
        cnt[tid] = 0;
        __syncthreads();
#pragma unroll
        for (int k = 0; k < EPB / 256; ++k) {
            int i = t0 + k * 256 + tid;
            if (i < P.E) {
                int bb = bk[k];
                int gpos = base[bb] + atomicAdd(&cnt[bb], 1);
                if (gpos < ESTRIDE) {   // overflow guard (never hits: 6sigma)
                    unsigned int colofs = (unsigned)(P.col[i] - bb * P.bspan);
                    P.ebuf[(size_t)bb * ESTRIDE + gpos] =
                        ((unsigned)P.row[i] & 0xFFFFu) | (colofs << 16);
                }
            }
        }
    } else if (u < P.npart + 16) {
        wprep_body(P.W1o, P.W1r, P.wf1, 128, (u - P.npart) * 256 + tid);
    } else if (u < P.npart + 32) {
        wprep_body(P.W2o, P.W2r, P.wf2, 128, (u - P.npart - 16) * 256 + tid);
    } else if (u < P.npart + 40) {
        wprep_body(P.W3o, P.W3r, P.wf3, 64, (u - P.npart - 32) * 256 + tid);
    } else {
        int i = (u - P.npart - 40) * 256 + tid;
        if (i < P.n4) {
            float4 v = P.x[i];
            uint2 o;
            o.x = (unsigned)f2bf(v.x) | ((unsigned)f2bf(v.y) << 16);
            o.y = (unsigned)f2bf(v.z) | ((unsigned)f2bf(v.w) << 16);
            P.xb2[i] = o;
        }
    }
}

// ---- P1: per-bucket fill with (col, row-window) counting sort --------------
__device__ void body_fillb(const KParams& P, int b, unsigned char* smem) {
    int* cnt    = (int*)smem;                    // 4096 ints
    int* scan_s = (int*)(smem + 16384);          // 257 ints
    int* wsum   = (int*)(smem + 17424);          // 4 ints
    const int tid = threadIdx.x;
    const int lane = tid & 63, wid = tid >> 6;
    __syncthreads();                             // smem reuse guard
    {
        int v = min(P.bcnt[tid], ESTRIDE);
        int ps = v;
#pragma unroll
        for (int off = 1; off < 64; off <<= 1) {
            int t = __shfl_up(ps, off);
            if (lane >= off) ps += t;
        }
        if (lane == 63) wsum[wid] = ps;
        __syncthreads();
        int wb = 0;
        for (int w = 0; w < wid; ++w) wb += wsum[w];
        int excl = wb + ps - v;
        scan_s[tid] = excl;
        if (tid == 255) scan_s[256] = excl + v;
    }
    for (int i = tid; i < 4096; i += 256) cnt[i] = 0;
    __syncthreads();
    const int cntb = min(P.bcnt[b], ESTRIDE);
    const int csr0 = scan_s[b];
    if (b == NBUCK - 1 && tid == 0) P.offs[P.N] = scan_s[256];
    const size_t eb0 = (size_t)b * ESTRIDE;
    for (int i = tid; i < cntb; i += 256) {
        const unsigned u = P.ebuf[eb0 + i];
        atomicAdd(&cnt[(int)(u >> 16) * 16 + (int)((u & 0xFFFFu) >> 12)], 1);
    }
    __syncthreads();
    int vv[16], s = 0;
#pragma unroll
    for (int r = 0; r < 16; ++r) { vv[r] = cnt[tid * 16 + r]; s += vv[r]; }
    int ps = s;
#pragma unroll
    for (int off = 1; off < 64; off <<= 1) {
        int t = __shfl_up(ps, off);
        if (lane >= off) ps += t;
    }
    if (lane == 63) wsum[wid] = ps;
    __syncthreads();
    int wb = 0;
    for (int w = 0; w < wid; ++w) wb += wsum[w];
    int excl = csr0 + wb + ps - s;
    const int node = b * P.bspan + tid;
    if (tid < P.bspan && node < P.N) {
        P.offs[node] = excl;
        P.deginv[node] = 1.0f / (float)(s + 1);
    }
#pragma unroll
    for (int r = 0; r < 16; ++r) { int t = vv[r]; cnt[tid * 16 + r] = excl; excl += t; }
    __syncthreads();
    for (int i = tid; i < cntb; i += 256) {
        const unsigned u = P.ebuf[eb0 + i];
        const int pos = atomicAdd(&cnt[(int)(u >> 16) * 16 + (int)((u & 0xFFFFu) >> 12)], 1);
        P.srow[pos] = (unsigned short)(u & 0xFFFFu);
    }
}

// ---- P2/P3: fused gather + MFMA GEMM (layers 1,2[,3-HR]), srow in LDS ------
__device__ void body_fused(const KParams& P, int tb, bool HR, unsigned char* smem) {
    unsigned short (*At)[136] = (unsigned short (*)[136])smem;        // 8704B
    unsigned short* sIdx = (unsigned short*)(smem + 8704);            // 768
    const unsigned short* __restrict__ xb = HR ? P.Ya : P.xbuf;
    const uint4* __restrict__ wfrag = HR ? P.wf2 : P.wf1;
    const float* __restrict__ bvec = HR ? P.b2 : P.b1;
    const int n = P.N;
    const int tid = threadIdx.x;
    const int m0 = tb * 32;
    const uint4* __restrict__ xb4 = (const uint4*)xb;

    __syncthreads();                  // smem reuse guard across iterations
    const int s0 = P.offs[m0];
    const int eAll = P.offs[min(m0 + 32, n)];
    const int cntE = eAll - s0;
    const bool staged = (cntE <= 768);
    for (int i = tid; i < cntE && i < 768; i += 256) sIdx[i] = P.srow[s0 + i];
    __syncthreads();
    const unsigned short* __restrict__ idxp = staged ? sIdx : P.srow;
    const int bias = staged ? s0 : 0;

#pragma unroll
    for (int rnd = 0; rnd < 2; ++rnd) {
        const int nl = rnd * 16 + (tid >> 4);
        const int lane = tid & 15;
        const int node = m0 + nl;
        if (node < n) {
            const size_t rb = (size_t)node * 16 + lane;
            uint4 sv = xb4[rb];
            float a0 = blo(sv.x), a1 = bhi(sv.x), a2 = blo(sv.y), a3 = bhi(sv.y);
            float a4 = blo(sv.z), a5 = bhi(sv.z), a6 = blo(sv.w), a7 = bhi(sv.w);
            const int s = P.offs[node] - bias, e = P.offs[node + 1] - bias;
            int p = s;
            for (; p + 4 <= e; p += 4) {
                const int r0 = idxp[p], r1 = idxp[p + 1];
                const int r2 = idxp[p + 2], r3 = idxp[p + 3];
                const uint4 v0 = xb4[(size_t)r0 * 16 + lane];
                const uint4 v1 = xb4[(size_t)r1 * 16 + lane];
                const uint4 v2 = xb4[(size_t)r2 * 16 + lane];
                const uint4 v3 = xb4[(size_t)r3 * 16 + lane];
                a0 += (blo(v0.x) + blo(v1.x)) + (blo(v2.x) + blo(v3.x));
                a1 += (bhi(v0.x) + bhi(v1.x)) + (bhi(v2.x) + bhi(v3.x));
                a2 += (blo(v0.y) + blo(v1.y)) + (blo(v2.y) + blo(v3.y));
                a3 += (bhi(v0.y) + bhi(v1.y)) + (bhi(v2.y) + bhi(v3.y));
                a4 += (blo(v0.z) + blo(v1.z)) + (blo(v2.z) + blo(v3.z));
                a5 += (bhi(v0.z) + bhi(v1.z)) + (bhi(v2.z) + bhi(v3.z));
                a6 += (blo(v0.w) + blo(v1.w)) + (blo(v2.w) + blo(v3.w));
                a7 += (bhi(v0.w) + bhi(v1.w)) + (bhi(v2.w) + bhi(v3.w));
            }
            for (; p < e; ++p) {
                const uint4 v = xb4[(size_t)idxp[p] * 16 + lane];
                a0 += blo(v.x); a1 += bhi(v.x); a2 += blo(v.y); a3 += bhi(v.y);
                a4 += blo(v.z); a5 += bhi(v.z); a6 += blo(v.w); a7 += bhi(v.w);
            }
            const float w = P.deginv[node];
            uint4 o;
            o.x = (unsigned)f2bf(a0 * w) | ((unsigned)f2bf(a1 * w) << 16);
            o.y = (unsigned)f2bf(a2 * w) | ((unsigned)f2bf(a3 * w) << 16);
            o.z = (unsigned)f2bf(a4 * w) | ((unsigned)f2bf(a5 * w) << 16);
            o.w = (unsigned)f2bf(a6 * w) | ((unsigned)f2bf(a7 * w) << 16);
            *(uint4*)&At[nl][lane * 8] = o;
        }
    }
    __syncthreads();

    const int w = tid >> 6, L = tid & 63;
    const int quad = L >> 4, l15 = L & 15;

    f32x4 acc[2][2];
#pragma unroll
    for (int mt = 0; mt < 2; ++mt)
#pragma unroll
        for (int u = 0; u < 2; ++u)
            acc[mt][u] = (f32x4){0.f, 0.f, 0.f, 0.f};

    const bf16x8 zf = {0, 0, 0, 0, 0, 0, 0, 0};
#pragma unroll
    for (int t = 0; t < 8; ++t) {
        bf16x8 bfr[2];
#pragma unroll
        for (int u = 0; u < 2; ++u)
            bfr[u] = *(const bf16x8*)&wfrag[(size_t)((t * 8 + (w * 2 + u)) * 64 + L)];
        const int koff = (t & 3) * 32 + quad * 8;
        bf16x8 af[2];
#pragma unroll
        for (int mt = 0; mt < 2; ++mt) {
            const int rl = mt * 16 + l15;
            if (t < 4) {
                af[mt] = *(const bf16x8*)&At[rl][koff];
            } else {
                const int r = m0 + rl;
                af[mt] = (r < n) ? *(const bf16x8*)(xb + (size_t)r * 128 + koff) : zf;
            }
        }
#pragma unroll
        for (int mt = 0; mt < 2; ++mt)
#pragma unroll
            for (int u = 0; u < 2; ++u)
                acc[mt][u] = __builtin_amdgcn_mfma_f32_16x16x32_bf16(
                    af[mt], bfr[u], acc[mt][u], 0, 0, 0);
    }

    float bb[2];
    bb[0] = bvec[w * 32 + l15];
    bb[1] = bvec[w * 32 + 16 + l15];

    if (!HR) {
#pragma unroll
        for (int mt = 0; mt < 2; ++mt)
#pragma unroll
            for (int u = 0; u < 2; ++u)
#pragma unroll
                for (int r4 = 0; r4 < 4; ++r4) {
                    const int r = m0 + mt * 16 + quad * 4 + r4;
                    if (r < n) {
                        float v = fmaxf(acc[mt][u][r4] + bb[u], 0.f);
                        P.Ya[(size_t)r * 128 + w * 32 + u * 16 + l15] = f2bf(v);
                    }
                }
    } else {
        __syncthreads();   // done reading At as Agg
#pragma unroll
        for (int mt = 0; mt < 2; ++mt)
#pragma unroll
            for (int u = 0; u < 2; ++u)
#pragma unroll
                for (int r4 = 0; r4 < 4; ++r4) {
                    const int rl = mt * 16 + quad * 4 + r4;
                    float v = fmaxf(acc[mt][u][r4] + bb[u], 0.f);
                    At[rl][w * 32 + u * 16 + l15] = f2bf(v);
                }
        __syncthreads();

        f32x4 accH[2], accR[2];
#pragma unroll
        for (int mt = 0; mt < 2; ++mt) {
            accH[mt] = (f32x4){0.f, 0.f, 0.f, 0.f};
            accR[mt] = (f32x4){0.f, 0.f, 0.f, 0.f};
        }
#pragma unroll
        for (int t = 0; t < 4; ++t) {
            const bf16x8 bo = *(const bf16x8*)&P.wf3[(size_t)((t * 4 + w) * 64 + L)];
            const bf16x8 br = *(const bf16x8*)&P.wf3[(size_t)(((t + 4) * 4 + w) * 64 + L)];
            const int koff = t * 32 + quad * 8;
            bf16x8 af[2];
#pragma unroll
            for (int mt = 0; mt < 2; ++mt)
                af[mt] = *(const bf16x8*)&At[mt * 16 + l15][koff];
#pragma unroll
            for (int mt = 0; mt < 2; ++mt) {
                accH[mt] = __builtin_amdgcn_mfma_f32_16x16x32_bf16(af[mt], bo, accH[mt], 0, 0, 0);
                accR[mt] = __builtin_amdgcn_mfma_f32_16x16x32_bf16(af[mt], br, accR[mt], 0, 0, 0);
            }
        }
        const float bb3 = P.b3v[w * 16 + l15];
#pragma unroll
        for (int mt = 0; mt < 2; ++mt)
#pragma unroll
            for (int r4 = 0; r4 < 4; ++r4) {
                const int r = m0 + mt * 16 + quad * 4 + r4;
                if (r < n) {
                    P.Hb[(size_t)r * 64 + w * 16 + l15] = f2bf(accH[mt][r4]);
                    P.Rb[(size_t)r * 64 + w * 16 + l15] = accR[mt][r4] + bb3;
                }
            }
    }
}

// ---- P4: layer-3 gather + log-softmax, srow in LDS -------------------------
__device__ void body_g3(const KParams& P, int tb, unsigned char* smem) {
    unsigned short* sIdx = (unsigned short*)smem;   // 512
    const int tid = threadIdx.x;
    const int m0 = tb * 16;
    const int n = P.N;
    const uint2* __restrict__ Hb2 = (const uint2*)P.Hb;
    const float4* __restrict__ R4 = (const float4*)P.Rb;

    __syncthreads();                  // smem reuse guard across iterations
    const int s0 = P.offs[m0];
    const int eAll = P.offs[min(m0 + 16, n)];
    const int cntE = eAll - s0;
    const bool staged = (cntE <= 512);
    for (int i = tid; i < cntE && i < 512; i += 256) sIdx[i] = P.srow[s0 + i];
    __syncthreads();
    const unsigned short* __restrict__ idxp = staged ? sIdx : P.srow;
    const int bias = staged ? s0 : 0;

    const int node = m0 + (tid >> 4);
    const int lane = tid & 15;
    if (node < n) {
        const size_t rb = (size_t)node * 16 + lane;
        uint2 sv = Hb2[rb];
        float a0 = blo(sv.x), a1 = bhi(sv.x), a2 = blo(sv.y), a3 = bhi(sv.y);
        const int s = P.offs[node] - bias, e = P.offs[node + 1] - bias;
        int p = s;
        for (; p + 4 <= e; p += 4) {
            const int r0 = idxp[p], r1 = idxp[p + 1], r2 = idxp[p + 2], r3 = idxp[p + 3];
            const uint2 v0 = Hb2[(size_t)r0 * 16 + lane];
            const uint2 v1 = Hb2[(size_t)r1 * 16 + lane];
            const uint2 v2 = Hb2[(size_t)r2 * 16 + lane];
            const uint2 v3 = Hb2[(size_t)r3 * 16 + lane];
            a0 += (blo(v0.x) + blo(v1.x)) + (blo(v2.x) + blo(v3.x));
            a1 += (bhi(v0.x) + bhi(v1.x)) + (bhi(v2.x) + bhi(v3.x));
            a2 += (blo(v0.y) + blo(v1.y)) + (blo(v2.y) + blo(v3.y));
            a3 += (bhi(v0.y) + bhi(v1.y)) + (bhi(v2.y) + bhi(v3.y));
        }
        for (; p < e; ++p) {
            const uint2 v = Hb2[(size_t)idxp[p] * 16 + lane];
            a0 += blo(v.x); a1 += bhi(v.x); a2 += blo(v.y); a3 += bhi(v.y);
        }
        const float w = P.deginv[node];
        const float4 r = R4[rb];
        float v0 = fmaxf(a0 * w + r.x, 0.f);
        float v1 = fmaxf(a1 * w + r.y, 0.f);
        float v2 = fmaxf(a2 * w + r.z, 0.f);
        float v3 = fmaxf(a3 * w + r.w, 0.f);
        float m = fmaxf(fmaxf(v0, v1), fmaxf(v2, v3));
        m = fmaxf(m, __shfl_xor(m, 1));
        m = fmaxf(m, __shfl_xor(m, 2));
        m = fmaxf(m, __shfl_xor(m, 4));
        m = fmaxf(m, __shfl_xor(m, 8));
        float s2 = __expf(v0 - m) + __expf(v1 - m) + __expf(v2 - m) + __expf(v3 - m);
        s2 += __shfl_xor(s2, 1);
        s2 += __shfl_xor(s2, 2);
        s2 += __shfl_xor(s2, 4);
        s2 += __shfl_xor(s2, 8);
        const float lse = m + __logf(s2);
        P.out[rb] = make_float4(v0 - lse, v1 - lse, v2 - lse, v3 - lse);
    }
}

__global__ __launch_bounds__(256) void k_all(KParams P) {
    __shared__ __align__(16) unsigned char smem[SMEM_BYTES];
    cg::grid_group grid = cg::this_grid();
    const bool all = (P.phase < 0);
    const int G = gridDim.x, bid = blockIdx.x;
    const int tid = threadIdx.x;

    if (all) {
        if (bid == 0 && tid < NBUCK) P.bcnt[tid] = 0;
        grid.sync();
    }
    if (all || P.phase == 0) {
        const int U0 = P.npart + 40 + (P.n4 + 255) / 256;
        for (int u = bid; u < U0; u += G) body_p0(P, u, smem);
    }
    if (all) grid.sync();
    if (all || P.phase == 1) {
        for (int u = bid; u < NBUCK; u += G) body_fillb(P, u, smem);
    }
    if (all) grid.sync();
    const int Gf = (P.N + 31) / 32;
    if (all || P.phase == 2) {
        for (int u = bid; u < Gf; u += G) body_fused(P, u, false, smem);
    }
    if (all) grid.sync();
    if (all || P.phase == 3) {
        for (int u = bid; u < Gf; u += G) body_fused(P, u, true, smem);
    }
    if (all) grid.sync();
    if (all || P.phase == 4) {
        const int Gg3 = (P.N + 15) / 16;
        for (int u = bid; u < Gg3; u += G) body_g3(P, u, smem);
    }
}

extern "C" void kernel_launch(void* const* d_in, const int* in_sizes, int n_in,
                              void* d_out, int out_size, void* d_ws, size_t ws_size,
                              hipStream_t stream) {
    const float* x   = (const float*)d_in[0];
    const int*   ei  = (const int*)d_in[1];

    const int N = in_sizes[0] / DK;   // 50000 (row index fits 16 bits)
    const int E = in_sizes[1] / 2;    // 800000

    int*   bcnt   = (int*)d_ws;                         // 256
    int*   offs   = bcnt + 256;                         // N+1
    float* deginv = (float*)(offs + ((N + 64) & ~63));  // N
    unsigned short* srow = (unsigned short*)(deginv + ((N + 63) & ~63)); // E ushort
    unsigned int* ebuf = (unsigned int*)(srow + ((E + 63) & ~63)); // 256*ESTRIDE
    uint4* wf1    = (uint4*)(ebuf + (size_t)NBUCK * ESTRIDE);  // 4096 uint4
    uint4* wf2    = wf1 + 4096;                         // 4096
    uint4* wf3    = wf2 + 4096;                         // 2048
    unsigned short* xbuf = (unsigned short*)(wf3 + 2048);   // N*128 bf16
    unsigned short* Ya   = xbuf + (size_t)N * 128;          // N*128 (layer1 out)
    unsigned short* Hb   = Ya + (size_t)N * 128;            // N*64 bf16 (H)
    float* Rb = (float*)(Hb + (size_t)N * 64);              // N*64 fp32 (R)

    KParams P;
    P.x = (const float4*)x; P.xb2 = (uint2*)xbuf;
    P.row = ei; P.col = ei + E;
    P.bcnt = bcnt; P.ebuf = ebuf;
    P.n4 = N * 32; P.E = E; P.bspan = (N + NBUCK - 1) / NBUCK;
    P.npart = (E + EPB - 1) / EPB; P.N = N;
    P.W1o = (const float*)d_in[2];  P.b1 = (const float*)d_in[3];
    P.W1r = (const float*)d_in[4];
    P.W2o = (const float*)d_in[5];  P.b2 = (const float*)d_in[6];
    P.W2r = (const float*)d_in[7];
    P.W3o = (const float*)d_in[8];  P.b3v = (const float*)d_in[9];
    P.W3r = (const float*)d_in[10];
    P.wf1 = wf1; P.wf2 = wf2; P.wf3 = wf3;
    P.offs = offs; P.deginv = deginv; P.srow = srow;
    P.xbuf = xbuf; P.Ya = Ya; P.Hb = Hb; P.Rb = Rb;
    P.out = (float4*)d_out;

    // cooperative path: one kernel, grid.sync between phases
    int occ = 0;
    hipError_t qe = hipOccupancyMaxActiveBlocksPerMultiprocessor(&occ, k_all, 256, 0);
    if (qe == hipSuccess && occ >= 2) {
        P.phase = -1;
        int grid = occ * 256;
        if (grid > 2048) grid = 2048;
        void* args[] = { (void*)&P };
        hipError_t le = hipLaunchCooperativeKernel((const void*)k_all, dim3(grid),
                                                   dim3(256), args, 0, stream);
        if (le == hipSuccess) return;
    }

    // fallback: R24-equivalent multi-dispatch (same bodies, same numerics)
    hipMemsetAsync(bcnt, 0, NBUCK * sizeof(int), stream);
    const int nxblk = (P.n4 + 255) / 256;
    const int Gf = (N + 31) / 32;
    const int Gg3 = (N + 15) / 16;
    KParams Q = P;
    Q.phase = 0; k_all<<<P.npart + 40 + nxblk, 256, 0, stream>>>(Q);
    Q.phase = 1; k_all<<<NBUCK, 256, 0, stream>>>(Q);
    Q.phase = 2; k_all<<<Gf, 256, 0, stream>>>(Q);
    Q.phase = 3; k_all<<<Gf, 256, 0, stream>>>(Q);
    Q.phase = 4; k_all<<<Gg3, 256, 0, stream>>>(Q);
}

// Round 11
// 201.020 us; speedup vs baseline: 1.2744x; 1.2744x over previous
//
#include <hip/hip_runtime.h>
#include <math.h>

// ClusterGCN 3-layer inference, MI355X — R26.
// R25 (cooperative mega-kernel) regressed 208->256: grid.sync on 8 XCDs costs
// far more than graph-captured launches. Reverted to R24 structure (208.1).
// R26 targets grid round-quantization: equal-duration blocks run in ~2 rounds
// (B=1563 > C~1024-1280), wasting ~ one block-duration of tail. (1) k_fused ->
// 16-node tiles (B=3125, delta halves; gather in ONE round, same 16-lane/node
// edge order -> bit-exact; GEMM M=16). (2) k_gather3 -> 128t/8-node blocks.
// (3) own-row X tile staged in LDS during gather (kills dependent global
// loads in GEMM X-operand; garbage rows masked as before).

constexpr int DK = 128;
constexpr int NBUCK = 256;
constexpr int ESTRIDE = 3584;   // max bucket count ~3136+6sigma~3470 < 3584
constexpr int EPB = 2048;       // edges per partition block (8/thread)

typedef __attribute__((ext_vector_type(8))) short bf16x8;
typedef __attribute__((ext_vector_type(4))) float f32x4;

__device__ inline unsigned short f2bf(float f) {
    unsigned int u; __builtin_memcpy(&u, &f, 4);
    unsigned int r = (u + 0x7FFFu + ((u >> 16) & 1u)) >> 16;
    return (unsigned short)r;
}
__device__ inline float blo(unsigned int u) {
    unsigned int t = u << 16; float f; __builtin_memcpy(&f, &t, 4); return f;
}
__device__ inline float bhi(unsigned int u) {
    unsigned int t = u & 0xffff0000u; float f; __builtin_memcpy(&f, &t, 4); return f;
}

// ------- merged prep: edge partition FIRST, weight swizzle, x->bf16 ---------
__device__ void wprep_body(const float* __restrict__ Wout, const float* __restrict__ Wroot,
                           uint4* __restrict__ frag, int dout, int tid) {
    int total = 8 * (dout >> 4) * 64;
    if (tid >= total) return;
    int L = tid & 63;
    int fu = (tid >> 6) % (dout >> 4);
    int t = (tid >> 6) / (dout >> 4);
    int quad = L >> 4, l15 = L & 15;
    int n = fu * 16 + l15;
    unsigned int p[4];
#pragma unroll
    for (int jj = 0; jj < 4; ++jj) {
        int k0 = t * 32 + quad * 8 + jj * 2;
        float v0 = (k0 < 128) ? Wout[k0 * dout + n] : Wroot[(k0 - 128) * dout + n];
        int k1 = k0 + 1;
        float v1 = (k1 < 128) ? Wout[k1 * dout + n] : Wroot[(k1 - 128) * dout + n];
        p[jj] = (unsigned)f2bf(v0) | ((unsigned)f2bf(v1) << 16);
    }
    frag[tid] = make_uint4(p[0], p[1], p[2], p[3]);
}

__global__ void k_prep(const float4* __restrict__ x, uint2* __restrict__ xb,
                       const int* __restrict__ row, const int* __restrict__ col,
                       int* __restrict__ bcnt, unsigned int* __restrict__ ebuf,
                       int n4, int E, int bspan, int npart,
                       const float* __restrict__ W1o, const float* __restrict__ W1r, uint4* wf1,
                       const float* __restrict__ W2o, const float* __restrict__ W2r, uint4* wf2,
                       const float* __restrict__ W3o, const float* __restrict__ W3r, uint4* wf3) {
    const int b = blockIdx.x;
    const int tid = threadIdx.x;
    if (b < npart) {
        // edge partition into fixed-stride buckets (runs first, overlaps rest)
        __shared__ int cnt[NBUCK];
        __shared__ int base[NBUCK];
        const int t0 = b * EPB;
        cnt[tid] = 0;
        __syncthreads();
        int bk[EPB / 256];
#pragma unroll
        for (int k = 0; k < EPB / 256; ++k) {
            int i = t0 + k * 256 + tid;
            int bb = -1;
            if (i < E) { bb = col[i] / bspan; atomicAdd(&cnt[bb], 1); }
            bk[k] = bb;
        }
        __syncthreads();
        base[tid] = cnt[tid] ? atomicAdd(&bcnt[tid], cnt[tid]) : 0;
        cnt[tid] = 0;
        __syncthreads();
#pragma unroll
        for (int k = 0; k < EPB / 256; ++k) {
            int i = t0 + k * 256 + tid;
            if (i < E) {
                int bb = bk[k];
                int gpos = base[bb] + atomicAdd(&cnt[bb], 1);
                if (gpos < ESTRIDE) {   // overflow guard (never hits: 6sigma margin)
                    unsigned int colofs = (unsigned)(col[i] - bb * bspan);
                    ebuf[(size_t)bb * ESTRIDE + gpos] =
                        ((unsigned)row[i] & 0xFFFFu) | (colofs << 16);
                }
            }
        }
    } else if (b < npart + 16) {
        wprep_body(W1o, W1r, wf1, 128, (b - npart) * 256 + tid);
    } else if (b < npart + 32) {
        wprep_body(W2o, W2r, wf2, 128, (b - npart - 16) * 256 + tid);
    } else if (b < npart + 40) {
        wprep_body(W3o, W3r, wf3, 64, (b - npart - 32) * 256 + tid);
    } else {
        int i = (b - npart - 40) * 256 + tid;
        if (i >= n4) return;
        float4 v = x[i];
        uint2 o;
        o.x = (unsigned)f2bf(v.x) | ((unsigned)f2bf(v.y) << 16);
        o.y = (unsigned)f2bf(v.z) | ((unsigned)f2bf(v.w) << 16);
        xb[i] = o;
    }
}

// Per-bucket fill with (col, row-window) counting sort, 512 threads.
__global__ __launch_bounds__(512)
void k_fillb(const unsigned int* __restrict__ ebuf,
             const int* __restrict__ bcnt, int* __restrict__ offs,
             float* __restrict__ deginv, unsigned short* __restrict__ srow,
             int n, int bspan) {
    __shared__ int cnt[4096];
    __shared__ int scan_s[NBUCK + 1];
    __shared__ int wsum[4];
    const int b = blockIdx.x, tid = threadIdx.x;
    const int lane = tid & 63, wid = tid >> 6;

    // prefix scan of (clamped) bucket counts -> CSR base per bucket (tid<256)
    int v = 0, ps = 0;
    if (tid < 256) {
        v = min(bcnt[tid], ESTRIDE);
        ps = v;
#pragma unroll
        for (int off = 1; off < 64; off <<= 1) {
            int t = __shfl_up(ps, off);
            if (lane >= off) ps += t;
        }
        if (lane == 63) wsum[wid] = ps;
    }
    __syncthreads();
    if (tid < 256) {
        int wb = 0;
        for (int w = 0; w < wid; ++w) wb += wsum[w];
        int excl = wb + ps - v;
        scan_s[tid] = excl;
        if (tid == 255) scan_s[256] = excl + v;
    }
    for (int i = tid; i < 4096; i += 512) cnt[i] = 0;
    __syncthreads();

    const int cntb = min(bcnt[b], ESTRIDE);
    const int csr0 = scan_s[b];
    if (b == NBUCK - 1 && tid == 0) offs[n] = scan_s[256];
    const size_t eb0 = (size_t)b * ESTRIDE;
    for (int i = tid; i < cntb; i += 512) {
        const unsigned u = ebuf[eb0 + i];
        atomicAdd(&cnt[(int)(u >> 16) * 16 + (int)((u & 0xFFFFu) >> 12)], 1);
    }
    __syncthreads();

    // per-node window prefix (tid<256 owns node tid's 16 windows)
    int vv[16], s = 0, ps2 = 0;
    if (tid < 256) {
#pragma unroll
        for (int r = 0; r < 16; ++r) { vv[r] = cnt[tid * 16 + r]; s += vv[r]; }
        ps2 = s;
#pragma unroll
        for (int off = 1; off < 64; off <<= 1) {
            int t = __shfl_up(ps2, off);
            if (lane >= off) ps2 += t;
        }
        if (lane == 63) wsum[wid] = ps2;
    }
    __syncthreads();
    if (tid < 256) {
        int wb = 0;
        for (int w = 0; w < wid; ++w) wb += wsum[w];
        int excl = csr0 + wb + ps2 - s;
        const int node = b * bspan + tid;
        if (tid < bspan && node < n) {
            offs[node] = excl;
            deginv[node] = 1.0f / (float)(s + 1);
        }
#pragma unroll
        for (int r = 0; r < 16; ++r) { int t = vv[r]; cnt[tid * 16 + r] = excl; excl += t; }
    }
    __syncthreads();
    for (int i = tid; i < cntb; i += 512) {
        const unsigned u = ebuf[eb0 + i];
        const int pos = atomicAdd(&cnt[(int)(u >> 16) * 16 + (int)((u & 0xFFFFu) >> 12)], 1);
        srow[pos] = (unsigned short)(u & 0xFFFFu);
    }
}

// ------- fused gather + MFMA GEMM, 16-node tiles (layers 1,2[,3-HR]) --------
// Block = 16 nodes, 256 threads. Phase 0: stage srow range (<=512) into LDS.
// Phase 1: ONE round gather (16 nodes x 16 lanes, uint4); own row -> Xt.
// Phase 2: Y[16x128] = relu([Agg|X]@Wf+b), Agg from At, X from Xt (LDS).
// If HR: Y tile -> At, then H/R GEMM. Garbage rows (node>=n) masked at store.
template <bool HR>
__global__ __launch_bounds__(256, 8)
void k_fused(const unsigned short* __restrict__ xb,
             const int* __restrict__ offs, const unsigned short* __restrict__ srow,
             const float* __restrict__ deginv,
             const uint4* __restrict__ wfrag, const float* __restrict__ bvec,
             unsigned short* __restrict__ y,
             const uint4* __restrict__ wfrag3, const float* __restrict__ b3,
             unsigned short* __restrict__ H, float* __restrict__ R, int n) {
    __shared__ unsigned short At[16][136];
    __shared__ unsigned short Xt[16][136];
    __shared__ unsigned short sIdx[512];
    const int tid = threadIdx.x;
    const int m0 = blockIdx.x * 16;
    const uint4* __restrict__ xb4 = (const uint4*)xb;

    // ---- phase 0: stage srow range into LDS (coalesced) ----
    const int s0 = offs[m0];
    const int eAll = offs[min(m0 + 16, n)];
    const int cntE = eAll - s0;
    const bool staged = (cntE <= 512);
    for (int i = tid; i < cntE && i < 512; i += 256) sIdx[i] = srow[s0 + i];
    __syncthreads();
    const unsigned short* __restrict__ idxp = staged ? sIdx : srow;
    const int bias = staged ? s0 : 0;

    // ---- phase 1: gather (ONE round: 16 nodes x 16 lanes) ----
    {
        const int nl = tid >> 4;         // 0..15
        const int lane = tid & 15;
        const int node = m0 + nl;
        if (node < n) {
            const size_t rb = (size_t)node * 16 + lane;
            uint4 sv = xb4[rb];
            *(uint4*)&Xt[nl][lane * 8] = sv;   // own row for GEMM X-operand
            float a0 = blo(sv.x), a1 = bhi(sv.x), a2 = blo(sv.y), a3 = bhi(sv.y);
            float a4 = blo(sv.z), a5 = bhi(sv.z), a6 = blo(sv.w), a7 = bhi(sv.w);
            const int s = offs[node] - bias, e = offs[node + 1] - bias;
            int p = s;
            for (; p + 4 <= e; p += 4) {
                const int r0 = idxp[p], r1 = idxp[p + 1];
                const int r2 = idxp[p + 2], r3 = idxp[p + 3];
                const uint4 v0 = xb4[(size_t)r0 * 16 + lane];
                const uint4 v1 = xb4[(size_t)r1 * 16 + lane];
                const uint4 v2 = xb4[(size_t)r2 * 16 + lane];
                const uint4 v3 = xb4[(size_t)r3 * 16 + lane];
                a0 += (blo(v0.x) + blo(v1.x)) + (blo(v2.x) + blo(v3.x));
                a1 += (bhi(v0.x) + bhi(v1.x)) + (bhi(v2.x) + bhi(v3.x));
                a2 += (blo(v0.y) + blo(v1.y)) + (blo(v2.y) + blo(v3.y));
                a3 += (bhi(v0.y) + bhi(v1.y)) + (bhi(v2.y) + bhi(v3.y));
                a4 += (blo(v0.z) + blo(v1.z)) + (blo(v2.z) + blo(v3.z));
                a5 += (bhi(v0.z) + bhi(v1.z)) + (bhi(v2.z) + bhi(v3.z));
                a6 += (blo(v0.w) + blo(v1.w)) + (blo(v2.w) + blo(v3.w));
                a7 += (bhi(v0.w) + bhi(v1.w)) + (bhi(v2.w) + bhi(v3.w));
            }
            for (; p < e; ++p) {
                const uint4 v = xb4[(size_t)idxp[p] * 16 + lane];
                a0 += blo(v.x); a1 += bhi(v.x); a2 += blo(v.y); a3 += bhi(v.y);
                a4 += blo(v.z); a5 += bhi(v.z); a6 += blo(v.w); a7 += bhi(v.w);
            }
            const float w = deginv[node];
            uint4 o;
            o.x = (unsigned)f2bf(a0 * w) | ((unsigned)f2bf(a1 * w) << 16);
            o.y = (unsigned)f2bf(a2 * w) | ((unsigned)f2bf(a3 * w) << 16);
            o.z = (unsigned)f2bf(a4 * w) | ((unsigned)f2bf(a5 * w) << 16);
            o.w = (unsigned)f2bf(a6 * w) | ((unsigned)f2bf(a7 * w) << 16);
            *(uint4*)&At[nl][lane * 8] = o;
        }
    }
    __syncthreads();

    // ---- phase 2: GEMM (M=16; 4 warps x 2 col-fragments) ----
    const int w = tid >> 6, L = tid & 63;
    const int quad = L >> 4, l15 = L & 15;

    f32x4 acc[2];
    acc[0] = (f32x4){0.f, 0.f, 0.f, 0.f};
    acc[1] = (f32x4){0.f, 0.f, 0.f, 0.f};

#pragma unroll
    for (int t = 0; t < 8; ++t) {
        bf16x8 bfr[2];
#pragma unroll
        for (int u = 0; u < 2; ++u)
            bfr[u] = *(const bf16x8*)&wfrag[(size_t)((t * 8 + (w * 2 + u)) * 64 + L)];
        const int koff = (t & 3) * 32 + quad * 8;
        const bf16x8 af = (t < 4) ? *(const bf16x8*)&At[l15][koff]
                                  : *(const bf16x8*)&Xt[l15][koff];
#pragma unroll
        for (int u = 0; u < 2; ++u)
            acc[u] = __builtin_amdgcn_mfma_f32_16x16x32_bf16(af, bfr[u], acc[u], 0, 0, 0);
    }

    float bb[2];
    bb[0] = bvec[w * 32 + l15];
    bb[1] = bvec[w * 32 + 16 + l15];

    if (!HR) {
#pragma unroll
        for (int u = 0; u < 2; ++u)
#pragma unroll
            for (int r4 = 0; r4 < 4; ++r4) {
                const int r = m0 + quad * 4 + r4;
                if (r < n) {
                    float v = fmaxf(acc[u][r4] + bb[u], 0.f);
                    y[(size_t)r * 128 + w * 32 + u * 16 + l15] = f2bf(v);
                }
            }
        return;
    }

    // ---- phase 3 (HR): Y2 tile -> At, then H/R GEMM ----
    __syncthreads();   // done reading At as Agg
#pragma unroll
    for (int u = 0; u < 2; ++u)
#pragma unroll
        for (int r4 = 0; r4 < 4; ++r4) {
            const int rl = quad * 4 + r4;
            float v = fmaxf(acc[u][r4] + bb[u], 0.f);
            At[rl][w * 32 + u * 16 + l15] = f2bf(v);
        }
    __syncthreads();

    f32x4 accH = (f32x4){0.f, 0.f, 0.f, 0.f};
    f32x4 accR = (f32x4){0.f, 0.f, 0.f, 0.f};
#pragma unroll
    for (int t = 0; t < 4; ++t) {
        const bf16x8 bo = *(const bf16x8*)&wfrag3[(size_t)((t * 4 + w) * 64 + L)];
        const bf16x8 br = *(const bf16x8*)&wfrag3[(size_t)(((t + 4) * 4 + w) * 64 + L)];
        const int koff = t * 32 + quad * 8;
        const bf16x8 af = *(const bf16x8*)&At[l15][koff];
        accH = __builtin_amdgcn_mfma_f32_16x16x32_bf16(af, bo, accH, 0, 0, 0);
        accR = __builtin_amdgcn_mfma_f32_16x16x32_bf16(af, br, accR, 0, 0, 0);
    }
    const float bb3 = b3[w * 16 + l15];
#pragma unroll
    for (int r4 = 0; r4 < 4; ++r4) {
        const int r = m0 + quad * 4 + r4;
        if (r < n) {
            H[(size_t)r * 64 + w * 16 + l15] = f2bf(accH[r4]);
            R[(size_t)r * 64 + w * 16 + l15] = accR[r4] + bb3;
        }
    }
}

// ------- layer 3 gather: 128 threads, 8 nodes, srow staged in LDS -----------
__global__ __launch_bounds__(128, 16)
void k_gather3(const uint2* __restrict__ Hb, const float4* __restrict__ R4,
               const int* __restrict__ offs, const unsigned short* __restrict__ srow,
               const float* __restrict__ deginv, float4* __restrict__ out, int n) {
    __shared__ unsigned short sIdx[256];
    const int tid = threadIdx.x;
    const int m0 = blockIdx.x * 8;
    const int s0 = offs[m0];
    const int eAll = offs[min(m0 + 8, n)];
    const int cntE = eAll - s0;
    const bool staged = (cntE <= 256);
    for (int i = tid; i < cntE && i < 256; i += 128) sIdx[i] = srow[s0 + i];
    __syncthreads();
    const unsigned short* __restrict__ idxp = staged ? sIdx : srow;
    const int bias = staged ? s0 : 0;

    const int node = m0 + (tid >> 4);
    const int lane = tid & 15;
    if (node >= n) return;
    const size_t rb = (size_t)node * 16 + lane;
    uint2 sv = Hb[rb];
    float a0 = blo(sv.x), a1 = bhi(sv.x), a2 = blo(sv.y), a3 = bhi(sv.y);
    const int s = offs[node] - bias, e = offs[node + 1] - bias;
    int p = s;
    for (; p + 4 <= e; p += 4) {
        const int r0 = idxp[p], r1 = idxp[p + 1], r2 = idxp[p + 2], r3 = idxp[p + 3];
        const uint2 v0 = Hb[(size_t)r0 * 16 + lane];
        const uint2 v1 = Hb[(size_t)r1 * 16 + lane];
        const uint2 v2 = Hb[(size_t)r2 * 16 + lane];
        const uint2 v3 = Hb[(size_t)r3 * 16 + lane];
        a0 += (blo(v0.x) + blo(v1.x)) + (blo(v2.x) + blo(v3.x));
        a1 += (bhi(v0.x) + bhi(v1.x)) + (bhi(v2.x) + bhi(v3.x));
        a2 += (blo(v0.y) + blo(v1.y)) + (blo(v2.y) + blo(v3.y));
        a3 += (bhi(v0.y) + bhi(v1.y)) + (bhi(v2.y) + bhi(v3.y));
    }
    for (; p < e; ++p) {
        const uint2 v = Hb[(size_t)idxp[p] * 16 + lane];
        a0 += blo(v.x); a1 += bhi(v.x); a2 += blo(v.y); a3 += bhi(v.y);
    }
    const float w = deginv[node];
    const float4 r = R4[rb];
    float v0 = fmaxf(a0 * w + r.x, 0.f);
    float v1 = fmaxf(a1 * w + r.y, 0.f);
    float v2 = fmaxf(a2 * w + r.z, 0.f);
    float v3 = fmaxf(a3 * w + r.w, 0.f);
    float m = fmaxf(fmaxf(v0, v1), fmaxf(v2, v3));
    m = fmaxf(m, __shfl_xor(m, 1));
    m = fmaxf(m, __shfl_xor(m, 2));
    m = fmaxf(m, __shfl_xor(m, 4));
    m = fmaxf(m, __shfl_xor(m, 8));
    float s2 = __expf(v0 - m) + __expf(v1 - m) + __expf(v2 - m) + __expf(v3 - m);
    s2 += __shfl_xor(s2, 1);
    s2 += __shfl_xor(s2, 2);
    s2 += __shfl_xor(s2, 4);
    s2 += __shfl_xor(s2, 8);
    const float lse = m + __logf(s2);
    out[rb] = make_float4(v0 - lse, v1 - lse, v2 - lse, v3 - lse);
}

extern "C" void kernel_launch(void* const* d_in, const int* in_sizes, int n_in,
                              void* d_out, int out_size, void* d_ws, size_t ws_size,
                              hipStream_t stream) {
    const float* x   = (const float*)d_in[0];
    const int*   ei  = (const int*)d_in[1];
    const float* W1o = (const float*)d_in[2];
    const float* b1  = (const float*)d_in[3];
    const float* W1r = (const float*)d_in[4];
    const float* W2o = (const float*)d_in[5];
    const float* b2  = (const float*)d_in[6];
    const float* W2r = (const float*)d_in[7];
    const float* W3o = (const float*)d_in[8];
    const float* b3  = (const float*)d_in[9];
    const float* W3r = (const float*)d_in[10];

    const int N = in_sizes[0] / DK;   // 50000 (row index fits 16 bits)
    const int E = in_sizes[1] / 2;    // 800000
    const int* row = ei;
    const int* col = ei + E;
    const int bspan = (N + NBUCK - 1) / NBUCK;   // 196

    int*   bcnt   = (int*)d_ws;                         // 256
    int*   offs   = bcnt + 256;                         // N+1
    float* deginv = (float*)(offs + ((N + 64) & ~63));  // N
    unsigned short* srow = (unsigned short*)(deginv + ((N + 63) & ~63)); // E ushort
    unsigned int* ebuf = (unsigned int*)(srow + ((E + 63) & ~63)); // 256*ESTRIDE
    uint4* wf1    = (uint4*)(ebuf + (size_t)NBUCK * ESTRIDE);  // 4096 uint4
    uint4* wf2    = wf1 + 4096;                         // 4096
    uint4* wf3    = wf2 + 4096;                         // 2048
    unsigned short* xbuf = (unsigned short*)(wf3 + 2048);   // N*128 bf16
    unsigned short* Ya   = xbuf + (size_t)N * 128;          // N*128 (layer1 out)
    unsigned short* Hb   = Ya + (size_t)N * 128;            // N*64 bf16 (H)
    float* Rb = (float*)(Hb + (size_t)N * 64);              // N*64 fp32 (R)
    float* out = (float*)d_out;

    const int n4 = N * 32;
    const int nxblk = (n4 + 255) / 256;
    const int npart = (E + EPB - 1) / EPB;   // 391

    hipMemsetAsync(bcnt, 0, NBUCK * sizeof(int), stream);
    // partition (first) + weight swizzles + x-convert, all independent blocks
    k_prep<<<npart + 40 + nxblk, 256, 0, stream>>>((const float4*)x, (uint2*)xbuf,
                                                   row, col, bcnt, ebuf,
                                                   n4, E, bspan, npart,
                                                   W1o, W1r, wf1, W2o, W2r, wf2,
                                                   W3o, W3r, wf3);
    k_fillb<<<NBUCK, 512, 0, stream>>>(ebuf, bcnt, offs, deginv, srow, N, bspan);

    const int Gf = (N + 15) / 16;      // fused layer grid (16 nodes/block)
    const int Gg3 = (N + 7) / 8;       // layer-3 gather (8 nodes/block, 128t)

    // layer 1: xbuf -> Ya (fused gather+gemm)
    k_fused<false><<<Gf, 256, 0, stream>>>(xbuf, offs, srow, deginv, wf1, b1, Ya,
                                           nullptr, nullptr, nullptr, nullptr, N);
    // layer 2 + layer-3 HR: Ya -> (H=Hb bf16, R=Rb fp32); Y2 never hits global
    k_fused<true><<<Gf, 256, 0, stream>>>(Ya, offs, srow, deginv, wf2, b2, nullptr,
                                          wf3, b3, Hb, Rb, N);
    // layer 3 gather + softmax
    k_gather3<<<Gg3, 128, 0, stream>>>((const uint2*)Hb, (const float4*)Rb,
                                       offs, srow, deginv, (float4*)out, N);
}